// Round 9
// baseline (328.883 us; speedup 1.0000x reference)
//
#include <hip/hip_runtime.h>

// CustomConv2d: 3x3 conv, stride 1, pad 1. B=32, Cin=128, H=W=56, Cout=256.
// fp32 in/out (round-1 NaN proved it); per-wave dtype self-detection keeps
// robustness without a separate serialized detect dispatch.
//
// Implicit GEMM, internally bf16. M=cout(256), N=b*h*w(100352), K=cin*9(1152).
// Round-14: empirical ladder: r9 (A+B LDS, counted vmcnt, 3-deep, 128x64
// waves) 86.5us/29% beats drain (109), no-LDS (141, TA-transaction-bound),
// 8-wave lockstep (93). Keep r9's PROVEN ledger (in-loop vmem = gl2lds16
// only + counted gates), change only geometry to make MFMA the binding
// resource:
//   - wave tile 128x128 (acc[8][8] = 256 AGPR): 16 ds_read_b128 per 64
//     MFMA = 0.25KB/MFMA (r9: 0.375). Per block-half: LDS 96KB ~= 860cyc
//     < MFMA 1240cyc/SIMD -> MFMA-bound for the first time.
//   - block 256x256, 4 waves (2M x 2N), ONE block/CU (LDS 3x32KB = 96KB),
//     exactly 1 wave/SIMD; __launch_bounds__(256,1) -> 512-reg budget, no
//     spill at ~400 total (r7's spill was the 256-cap under (256,2))
//   - grid 392 = 8x49, XCD-swizzled; K = 36 halves of 32, h=(dh*3+dw)*4+q
//   - 3-deep pipeline: stage h+2 at top of body h; gate vmcnt(8) at end
//     (h+1 landed, h+2's 8 loads stay in flight); vmcnt(0) only at h=34
//   - same XOR chunk swizzle (0 bank conflicts measured), same repacks

typedef __attribute__((ext_vector_type(8))) short short8;
typedef __attribute__((ext_vector_type(4))) float floatx4;

typedef __attribute__((address_space(1))) const void* gas_ptr;
typedef __attribute__((address_space(3))) void* las_ptr;

__device__ static inline void gl2lds16(const void* g, void* l) {
    __builtin_amdgcn_global_load_lds((gas_ptr)g, (las_ptr)l, 16, 0, 0);
}

__device__ static inline float bf2f(unsigned short u) {
    union { unsigned int i; float f; } x; x.i = ((unsigned int)u) << 16; return x.f;
}
__device__ static inline unsigned short f2bf(float f) {
    union { float f; unsigned int i; } x; x.f = f;
    unsigned int r = (x.i + 0x7FFFu + ((x.i >> 16) & 1u)) >> 16;  // RNE
    return (unsigned short)r;
}

// Per-wave dtype sniff: low halves of fp32 words are random mantissa bits
// (~19% plausible bf16 exponents); true bf16 data is ~100% plausible.
// Uniform across the wave via ballot; requires all 64 lanes active.
__device__ static inline bool wave_detect_bf16(const unsigned int* __restrict__ p) {
    const int lane = threadIdx.x & 63;
    int cnt = 0;
#pragma unroll
    for (int r = 0; r < 4; ++r) {
        unsigned int w = p[r * 64 + lane];
        unsigned short lo = (unsigned short)(w & 0xFFFFu);
        int e = (lo >> 7) & 0xFF;
        bool plaus = (lo == 0) || (e >= 96 && e <= 144);
        cnt += (int)__popcll(__ballot(plaus));
    }
    return cnt >= 205;   // >=80% of 256 sampled halves
}

// ---------------- weight repack -> [9][256][128] bf16 ----------------------
__global__ void wt_repack(const void* __restrict__ wsrc,
                          unsigned short* __restrict__ wt) {
    const bool isbf = wave_detect_bf16((const unsigned int*)wsrc);
    int idx = blockIdx.x * 256 + threadIdx.x;       // 294912 total, grid=1152
    int ci  = idx & 127;
    int co  = (idx >> 7) & 255;
    int off = idx >> 15;                            // 0..8 = dh*3+dw
    size_t s = (size_t)(co * 128 + ci) * 9 + off;
    float v = isbf ? bf2f(((const unsigned short*)wsrc)[s])
                   : ((const float*)wsrc)[s];
    wt[idx] = f2bf(v);
}

// ------- x NCHW -> padded NHWC bf16 [32][58][58][128], LDS transpose -------
__global__ __launch_bounds__(256) void x_repack(
    const void* __restrict__ xsrc, unsigned short* __restrict__ xp) {
    __shared__ unsigned short tile[56 * 130];   // pad 130: conflict-free
    const int bh  = blockIdx.x;                 // 32*58 blocks
    const int b   = bh / 58, hp = bh - b * 58;  // hp in [0,58)
    const int tid = threadIdx.x;
    unsigned short* row = xp + (size_t)(b * 58 + hp) * 58 * 128;
    if (hp == 0 || hp == 57) {                  // top/bottom pad rows
        uint4 z; z.x = z.y = z.z = z.w = 0u;
        uint4* r = (uint4*)row;
        for (int t = tid; t < 928; t += 256) r[t] = z;
        return;
    }
    const bool isbf = wave_detect_bf16((const unsigned int*)xsrc);
    const int h = hp - 1;
    if (isbf) {
        const unsigned short* xs =
            (const unsigned short*)xsrc + (size_t)b * 128 * 3136 + h * 56;
#pragma unroll
        for (int it = 0; it < 7; ++it) {        // 1792 items = 128ci x 14 w4
            int idx = it * 256 + tid;
            int ci = idx / 14, w4 = idx - ci * 14;
            ushort4 v = *(const ushort4*)(xs + (size_t)ci * 3136 + w4 * 4);
            tile[(w4 * 4 + 0) * 130 + ci] = v.x;
            tile[(w4 * 4 + 1) * 130 + ci] = v.y;
            tile[(w4 * 4 + 2) * 130 + ci] = v.z;
            tile[(w4 * 4 + 3) * 130 + ci] = v.w;
        }
    } else {
        const float* xs = (const float*)xsrc + (size_t)b * 128 * 3136 + h * 56;
#pragma unroll
        for (int it = 0; it < 7; ++it) {
            int idx = it * 256 + tid;
            int ci = idx / 14, w4 = idx - ci * 14;
            float4 v = *(const float4*)(xs + (size_t)ci * 3136 + w4 * 4);
            tile[(w4 * 4 + 0) * 130 + ci] = f2bf(v.x);
            tile[(w4 * 4 + 1) * 130 + ci] = f2bf(v.y);
            tile[(w4 * 4 + 2) * 130 + ci] = f2bf(v.z);
            tile[(w4 * 4 + 3) * 130 + ci] = f2bf(v.w);
        }
    }
    __syncthreads();
#pragma unroll
    for (int it = 0; it < 4; ++it) {
        int k = it * 256 + tid;                 // 928 chunks of 16B
        if (k >= 928) break;
        int wq = k >> 4, cc = k & 15;
        uint4 v;
        if (wq == 0 || wq == 57) { v.x = v.y = v.z = v.w = 0u; }
        else {
            const unsigned short* p = &tile[(wq - 1) * 130 + cc * 8];
            union { unsigned short s[8]; uint4 u; } pk;
#pragma unroll
            for (int j = 0; j < 8; ++j) pk.s[j] = p[j];
            v = pk.u;
        }
        *(uint4*)(row + wq * 128 + cc * 8) = v;
    }
}

// -------- main: 4-wave 128x128-per-wave implicit GEMM, 256x256 tile --------
// K decomposition: 36 "halves" h = off*4 + q; off=h>>2 (0..8 = dh*3+dw),
// k-range within off = q*32 (q = h&3). Half-buffer (32KB): A[256 cout][32k]
// bf16 at +0 (16KB), B[256 n][32k] bf16 at +16384 (16KB). Rows are 64B;
// phys 16B chunk p of row r holds logical k-chunk p ^ (((r&15)>>1)&3).
__global__ __launch_bounds__(256, 1) void conv_mfma(
    const unsigned short* __restrict__ xp,   // [32][58][58][128] bf16
    const unsigned short* __restrict__ wt,   // [9][256][128] bf16
    const void* __restrict__ bias,           // [256] fp32 or bf16
    void* __restrict__ out,                  // [32][256][56][56] fp32 or bf16
    const void* __restrict__ xorig)          // for dtype sniff only
{
    __shared__ __align__(16) char lds[98304];   // 3 half-buffers x 32KB
    const int tid   = threadIdx.x;
    const int lane  = tid & 63;
    const int wv    = tid >> 6;        // 0..3
    const int bid   = blockIdx.x;
    const int ntile = (bid & 7) * 49 + (bid >> 3);   // XCD swizzle, 392=8x49

    const bool isbf = wave_detect_bf16((const unsigned int*)xorig);

    // ---- staging setup (8 x 1KB chunks per wave per half: 4 A + 4 B) -----
    // A half = 16 chunks (256 cout rows), B half = 16 chunks (256 n rows).
    // Wave wv stages A chunks wv*4+s and B chunks wv*4+s (s=0..3). Chunk c
    // covers LDS rows [c*16, c*16+16); lane writes row c*16 + (lane>>2),
    // phys 16B slot lane&3 holding logical k-chunk clg = (lane&3)^((lane>>3)&3)
    // -> LDS dest = chunkbase + lane*16 (linear, as gl2lds16 requires).
    const int clg  = (lane & 3) ^ ((lane >> 3) & 3);
    const int rsub = lane >> 2;
    unsigned sbA[4], sbB[4];
    int dbA[4], dbB[4];
#pragma unroll
    for (int s = 0; s < 4; ++s) {
        const int c  = wv * 4 + s;
        const int co = c * 16 + rsub;
        sbA[s] = (unsigned)(co * 256 + clg * 16);          // byte into wt
        dbA[s] = c * 1024;
        const int n = ntile * 256 + c * 16 + rsub;
        const int b = n / 3136, rem = n - b * 3136;
        const int hh = rem / 56, ww = rem - hh * 56;
        sbB[s] = (unsigned)(((b * 58 + hh) * 58 + ww) * 256 + clg * 16);
        dbB[s] = 16384 + c * 1024;
    }

    // ---- fragment read setup ----------------------------------------------
    const int fr = lane & 15;
    const int ph = (lane >> 4) ^ ((fr >> 1) & 3);
    const int wm = wv >> 1;            // 0..1  (M: 128 couts per wave)
    const int wn = wv & 1;             // 0..1  (N: 128 cols per wave)
    const int aOff = (wm * 128 + fr) * 64 + ph * 16;          // + i*1024
    const int bOff = 16384 + (wn * 128 + fr) * 64 + ph * 16;  // + j*1024

    floatx4 acc[8][8] = {};

    // ---- prologue: stage halves 0,1 (off=0 -> dA=dB=q*64) -----------------
#pragma unroll
    for (int h = 0; h < 2; ++h) {
        char* lb = lds + h * 32768;
        const int d = h * 64;
#pragma unroll
        for (int s = 0; s < 4; ++s)
            gl2lds16((const char*)wt + sbA[s] + d, lb + dbA[s]);
#pragma unroll
        for (int s = 0; s < 4; ++s)
            gl2lds16((const char*)xp + sbB[s] + d, lb + dbB[s]);
    }
    __builtin_amdgcn_s_waitcnt(0x3F78);   // vmcnt(8): half 0 landed
    __builtin_amdgcn_s_barrier();

    // ---- main loop: 36 halves ---------------------------------------------
    int bf_ = 0, st_ = 2;                 // h%3, (h+2)%3
#pragma unroll 3
    for (int h = 0; h < 36; ++h) {
        const char* la = lds + bf_ * 32768;
        // stage h+2 into buf (h+2)%3 (read at h-1, retired at h-1's barrier)
        if (h < 34) {
            char* sd = lds + st_ * 32768;
            const int hn  = h + 2;
            const int off = hn >> 2, q = hn & 3;
            const int dA  = off * 65536 + q * 64;
            const int dh_ = off / 3, dw_ = off - dh_ * 3;
            const int dB  = (dh_ * 58 + dw_) * 256 + q * 64;
#pragma unroll
            for (int s = 0; s < 4; ++s)
                gl2lds16((const char*)wt + sbA[s] + dA, sd + dbA[s]);
#pragma unroll
            for (int s = 0; s < 4; ++s)
                gl2lds16((const char*)xp + sbB[s] + dB, sd + dbB[s]);
        }
        short8 af[8], bf[8];
#pragma unroll
        for (int i = 0; i < 8; ++i)
            af[i] = *(const short8*)(la + aOff + i * 1024);
#pragma unroll
        for (int j = 0; j < 8; ++j)
            bf[j] = *(const short8*)(la + bOff + j * 1024);
        __builtin_amdgcn_s_setprio(1);
#pragma unroll
        for (int i = 0; i < 8; ++i)
#pragma unroll
            for (int j = 0; j < 8; ++j)
                acc[i][j] = __builtin_amdgcn_mfma_f32_16x16x32_bf16(
                    af[i], bf[j], acc[i][j], 0, 0, 0);
        __builtin_amdgcn_s_setprio(0);
        // counted gate: h+1 resident before next iteration's reads; h+2's
        // 8 loads stay in flight across the barrier.
        if (h < 34) {
            __builtin_amdgcn_s_waitcnt(0x3F78);   // vmcnt(8)
            __builtin_amdgcn_s_barrier();
        } else if (h == 34) {
            __builtin_amdgcn_s_waitcnt(0x3F70);   // vmcnt(0): h35 landed
            __builtin_amdgcn_s_barrier();
        }
        bf_ = (bf_ == 2) ? 0 : bf_ + 1;
        st_ = (st_ == 2) ? 0 : st_ + 1;
    }

    // ---- epilogue: D[row=cout(quad*4+reg)][col=spatial(lane&15)] ----------
    const int q4 = (lane >> 4) << 2;
    int nb[8], ns[8];
#pragma unroll
    for (int j = 0; j < 8; ++j) {
        const int n = ntile * 256 + wn * 128 + j * 16 + fr;
        nb[j] = n / 3136;
        ns[j] = n - nb[j] * 3136;
    }
#pragma unroll
    for (int i = 0; i < 8; ++i) {
        const int co = wm * 128 + i * 16 + q4;
        float bv[4];
        if (isbf) {
            const ushort4 bb = *(const ushort4*)((const unsigned short*)bias + co);
            bv[0] = bf2f(bb.x); bv[1] = bf2f(bb.y);
            bv[2] = bf2f(bb.z); bv[3] = bf2f(bb.w);
        } else {
            const float4 bb = *(const float4*)((const float*)bias + co);
            bv[0] = bb.x; bv[1] = bb.y; bv[2] = bb.z; bv[3] = bb.w;
        }
#pragma unroll
        for (int j = 0; j < 8; ++j) {
#pragma unroll
            for (int r = 0; r < 4; ++r) {
                const float v = acc[i][j][r] + bv[r];
                const size_t o = (size_t)nb[j] * 802816 +
                                 (size_t)(co + r) * 3136 + ns[j];
                if (isbf) ((unsigned short*)out)[o] = f2bf(v);
                else      ((float*)out)[o] = v;
            }
        }
    }
}

// ---------------- fallback: naive direct conv fp32 (if ws too small) -------
__global__ void conv_naive(const float* __restrict__ x,
                           const float* __restrict__ w,
                           const float* __restrict__ bias,
                           float* __restrict__ out) {
    long long i = (long long)blockIdx.x * 256 + threadIdx.x;
    if (i >= 25690112LL) return;
    int wo = (int)(i % 56); long long t = i / 56;
    int ho = (int)(t % 56); t /= 56;
    int co = (int)(t % 256); int b = (int)(t / 256);
    float acc = bias[co];
    for (int ci = 0; ci < 128; ++ci)
        for (int dh = 0; dh < 3; ++dh) {
            int hi = ho + dh - 1; if ((unsigned)hi >= 56u) continue;
            for (int dw = 0; dw < 3; ++dw) {
                int wi = wo + dw - 1; if ((unsigned)wi >= 56u) continue;
                acc += x[((size_t)(b * 128 + ci) * 56 + hi) * 56 + wi] *
                       w[((co * 128 + ci) * 3 + dh) * 3 + dw];
            }
        }
    out[i] = acc;
}

extern "C" void kernel_launch(void* const* d_in, const int* in_sizes, int n_in,
                              void* d_out, int out_size, void* d_ws, size_t ws_size,
                              hipStream_t stream) {
    const void* x    = d_in[0];
    const void* w    = d_in[1];
    const void* bias = d_in[2];
    // d_in[3] = approximate (scalar, does not affect exact math) — unused.

    const size_t xp_bytes = (size_t)32 * 58 * 58 * 128 * 2;   // 27,557,888
    const size_t wt_off   = xp_bytes;
    const size_t wt_bytes = (size_t)9 * 256 * 128 * 2;        // 589,824
    const size_t need     = wt_off + wt_bytes;

    if (ws_size >= need) {
        unsigned short* xp = (unsigned short*)d_ws;
        unsigned short* wt = (unsigned short*)((char*)d_ws + wt_off);
        x_repack<<<32 * 58, 256, 0, stream>>>(x, xp);
        wt_repack<<<1152, 256, 0, stream>>>(w, wt);
        conv_mfma<<<dim3(392, 1, 1), 256, 0, stream>>>(xp, wt, bias, d_out, x);
    } else {
        conv_naive<<<(25690112 + 255) / 256, 256, 0, stream>>>(
            (const float*)x, (const float*)w, (const float*)bias, (float*)d_out);
    }
}

// Round 11
// 231.091 us; speedup vs baseline: 1.4232x; 1.4232x over previous
//
#include <hip/hip_runtime.h>

// CustomConv2d: 3x3 conv, stride 1, pad 1. B=32, Cin=128, H=W=56, Cout=256.
// fp32 in/out (round-1 NaN proved it); per-wave dtype self-detection keeps
// robustness without a separate serialized detect dispatch.
//
// Implicit GEMM, internally bf16. M=cout(256), N=b*h*w(100352), K=cin*9(1152).
// Round-16: resubmission of round-15 (container failed twice before running
// it; audit re-verified barrier uniformity, read/overwrite ordering, the
// vmem ordering invariant, and exact-fit bounds — see session notes).
// Ladder: r9 (A+B LDS, 3-deep counted, 128x64) 86.5us/29% is LDS-BW-bound
// (~144KB LDS traffic per CU-half vs ~550cyc MFMA). This kernel cuts LDS
// traffic 3x (A -> registers) while keeping counted-pipeline semantics
// WITHOUT any manual vmcnt:
//   - wt in FRAGMENT ORDER: wave's A-operand = coalesced 1KB plain load
//     from L2-hot 576KB, double-buffered in regs (afA/afB ping-pong)
//   - B: LDS 3 x 8KB buffers via gl2lds16, staged 2 halves ahead
//   - ORDERING INVARIANT replaces the vmcnt ledger: per body, B-stage(h+2)
//     is issued BEFORE the A(h+1) loads (pinned by sched_barrier(0)).
//     vmem retires in order (m135), so the compiler's own wait for A(h)
//     before body-h MFMAs implies B(h+1) retired; the raw s_barrier after
//     the MFMAs makes that block-wide before anyone reads buffer (h+1).
//     Only full drain: one __syncthreads() in the prologue.
//   - per body: 2 gl2lds16 + 8 plain A-loads + 4 ds_read_b128 + 32 MFMA;
//     LDS/CU-slot 48KB (~565cyc) vs r9 144KB (~1700cyc) -> MFMA-bound
//   - regs mirror r12's measured 124 VGPR + 128 AGPR = 252 <= (256,2) cap
//     -> 2 blocks/CU, unsynchronized blocks fill each other's bubbles
//   - same B XOR chunk swizzle (0 conflicts measured), XCD swizzle 784=8x98

typedef __attribute__((ext_vector_type(8))) short short8;
typedef __attribute__((ext_vector_type(4))) float floatx4;

typedef __attribute__((address_space(1))) const void* gas_ptr;
typedef __attribute__((address_space(3))) void* las_ptr;

__device__ static inline void gl2lds16(const void* g, void* l) {
    __builtin_amdgcn_global_load_lds((gas_ptr)g, (las_ptr)l, 16, 0, 0);
}

__device__ static inline float bf2f(unsigned short u) {
    union { unsigned int i; float f; } x; x.i = ((unsigned int)u) << 16; return x.f;
}
__device__ static inline unsigned short f2bf(float f) {
    union { float f; unsigned int i; } x; x.f = f;
    unsigned int r = (x.i + 0x7FFFu + ((x.i >> 16) & 1u)) >> 16;  // RNE
    return (unsigned short)r;
}

// Per-wave dtype sniff: low halves of fp32 words are random mantissa bits
// (~19% plausible bf16 exponents); true bf16 data is ~100% plausible.
// Uniform across the wave via ballot; requires all 64 lanes active.
__device__ static inline bool wave_detect_bf16(const unsigned int* __restrict__ p) {
    const int lane = threadIdx.x & 63;
    int cnt = 0;
#pragma unroll
    for (int r = 0; r < 4; ++r) {
        unsigned int w = p[r * 64 + lane];
        unsigned short lo = (unsigned short)(w & 0xFFFFu);
        int e = (lo >> 7) & 0xFF;
        bool plaus = (lo == 0) || (e >= 96 && e <= 144);
        cnt += (int)__popcll(__ballot(plaus));
    }
    return cnt >= 205;   // >=80% of 256 sampled halves
}

// ------ weight repack -> fragment order [36][2][8][64] 16B chunks ---------
// Chunk (h=off*4+q, wm, i, lane) holds A[co=wm*128+i*16+(lane&15)]
// [ci=q*32+(lane>>4)*8 .. +8) as 8 bf16. conv_mfma lane l then loads its
// MFMA A-fragment at ushort index h*8192 + wm*4096 + i*512 + l*8.
__global__ void wt_repack(const void* __restrict__ wsrc,
                          unsigned short* __restrict__ wt) {
    const bool isbf = wave_detect_bf16((const unsigned int*)wsrc);
    int idx  = blockIdx.x * 256 + threadIdx.x;   // 36864 chunks, grid=144
    int lane = idx & 63;
    int i    = (idx >> 6) & 7;
    int wm   = (idx >> 9) & 1;
    int q    = (idx >> 10) & 3;
    int off  = idx >> 12;                        // 0..8 = dh*3+dw
    int co   = wm * 128 + i * 16 + (lane & 15);
    int ci0  = q * 32 + (lane >> 4) * 8;
    union { unsigned short s[8]; uint4 u; } pk;
#pragma unroll
    for (int e = 0; e < 8; ++e) {
        size_t s = (size_t)(co * 128 + ci0 + e) * 9 + off;
        float v = isbf ? bf2f(((const unsigned short*)wsrc)[s])
                       : ((const float*)wsrc)[s];
        pk.s[e] = f2bf(v);
    }
    *(uint4*)(wt + (size_t)idx * 8) = pk.u;
}

// ------- x NCHW -> padded NHWC bf16 [32][58][58][128], LDS transpose -------
__global__ __launch_bounds__(256) void x_repack(
    const void* __restrict__ xsrc, unsigned short* __restrict__ xp) {
    __shared__ unsigned short tile[56 * 130];   // pad 130: conflict-free
    const int bh  = blockIdx.x;                 // 32*58 blocks
    const int b   = bh / 58, hp = bh - b * 58;  // hp in [0,58)
    const int tid = threadIdx.x;
    unsigned short* row = xp + (size_t)(b * 58 + hp) * 58 * 128;
    if (hp == 0 || hp == 57) {                  // top/bottom pad rows
        uint4 z; z.x = z.y = z.z = z.w = 0u;
        uint4* r = (uint4*)row;
        for (int t = tid; t < 928; t += 256) r[t] = z;
        return;
    }
    const bool isbf = wave_detect_bf16((const unsigned int*)xsrc);
    const int h = hp - 1;
    if (isbf) {
        const unsigned short* xs =
            (const unsigned short*)xsrc + (size_t)b * 128 * 3136 + h * 56;
#pragma unroll
        for (int it = 0; it < 7; ++it) {        // 1792 items = 128ci x 14 w4
            int idx = it * 256 + tid;
            int ci = idx / 14, w4 = idx - ci * 14;
            ushort4 v = *(const ushort4*)(xs + (size_t)ci * 3136 + w4 * 4);
            tile[(w4 * 4 + 0) * 130 + ci] = v.x;
            tile[(w4 * 4 + 1) * 130 + ci] = v.y;
            tile[(w4 * 4 + 2) * 130 + ci] = v.z;
            tile[(w4 * 4 + 3) * 130 + ci] = v.w;
        }
    } else {
        const float* xs = (const float*)xsrc + (size_t)b * 128 * 3136 + h * 56;
#pragma unroll
        for (int it = 0; it < 7; ++it) {
            int idx = it * 256 + tid;
            int ci = idx / 14, w4 = idx - ci * 14;
            float4 v = *(const float4*)(xs + (size_t)ci * 3136 + w4 * 4);
            tile[(w4 * 4 + 0) * 130 + ci] = f2bf(v.x);
            tile[(w4 * 4 + 1) * 130 + ci] = f2bf(v.y);
            tile[(w4 * 4 + 2) * 130 + ci] = f2bf(v.z);
            tile[(w4 * 4 + 3) * 130 + ci] = f2bf(v.w);
        }
    }
    __syncthreads();
#pragma unroll
    for (int it = 0; it < 4; ++it) {
        int k = it * 256 + tid;                 // 928 chunks of 16B
        if (k >= 928) break;
        int wq = k >> 4, cc = k & 15;
        uint4 v;
        if (wq == 0 || wq == 57) { v.x = v.y = v.z = v.w = 0u; }
        else {
            const unsigned short* p = &tile[(wq - 1) * 130 + cc * 8];
            union { unsigned short s[8]; uint4 u; } pk;
#pragma unroll
            for (int j = 0; j < 8; ++j) pk.s[j] = p[j];
            v = pk.u;
        }
        *(uint4*)(row + wq * 128 + cc * 8) = v;
    }
}

// -------- main: 4-wave 128x64-per-wave implicit GEMM, 256x128 tile ---------
// A from global (fragment-order wt, register ping-pong, PLAIN loads); B via
// LDS 3-deep 8KB buffers staged 2 halves ahead. h=(dh*3+dw)*4+q, 36 halves.
__global__ __launch_bounds__(256, 2) void conv_mfma(
    const unsigned short* __restrict__ xp,   // [32][58][58][128] bf16
    const unsigned short* __restrict__ wt,   // fragment-order, 589824 B
    const void* __restrict__ bias,           // [256] fp32 or bf16
    void* __restrict__ out,                  // [32][256][56][56] fp32 or bf16
    const void* __restrict__ xorig)          // for dtype sniff only
{
    __shared__ __align__(16) char lds[24576];   // 3 B-buffers x 8KB
    const int tid   = threadIdx.x;
    const int lane  = tid & 63;
    const int wv    = tid >> 6;        // 0..3
    const int bid   = blockIdx.x;
    const int ntile = (bid & 7) * 98 + (bid >> 3);   // XCD swizzle, 784=8x98

    const bool isbf = wave_detect_bf16((const unsigned int*)xorig);

    // ---- B staging setup (2 x 1KB chunks per wave per half) --------------
    const int clg  = (lane & 3) ^ ((lane >> 3) & 3);
    const int rsub = lane >> 2;
    unsigned sbB[2]; int dbB[2];
#pragma unroll
    for (int s = 0; s < 2; ++s) {
        const int c = wv * 2 + s;
        const int n = ntile * 128 + c * 16 + rsub;
        const int b = n / 3136, rem = n - b * 3136;
        const int hh = rem / 56, ww = rem - hh * 56;
        sbB[s] = (unsigned)(((b * 58 + hh) * 58 + ww) * 256 + clg * 16);
        dbB[s] = c * 1024;
    }

    // ---- fragment setup ---------------------------------------------------
    const int fr = lane & 15;
    const int ph = (lane >> 4) ^ ((fr >> 1) & 3);
    const int wm = wv >> 1;            // 0..1  (M: 128 couts per wave)
    const int wn = wv & 1;             // 0..1  (N: 64 cols per wave)
    const int bOff = (wn * 64 + fr) * 64 + ph * 16;   // + j*1024
    const int aSub = wm * 4096 + lane * 8;            // ushort units

    floatx4 acc[8][4] = {};
    short8 afA[8], afB[8];

    // ---- prologue: stage B(0),B(1); then A(0)->afA; full drain once ------
    gl2lds16((const char*)xp + sbB[0], lds + dbB[0]);
    gl2lds16((const char*)xp + sbB[1], lds + dbB[1]);
    gl2lds16((const char*)xp + sbB[0] + 64, lds + 8192 + dbB[0]);
    gl2lds16((const char*)xp + sbB[1] + 64, lds + 8192 + dbB[1]);
    __builtin_amdgcn_sched_barrier(0);
#pragma unroll
    for (int i_ = 0; i_ < 8; ++i_)
        afA[i_] = *(const short8*)(wt + aSub + i_ * 512);
    __syncthreads();   // the ONLY full drain (vmcnt(0)+lgkmcnt(0)+barrier)

// Body for half H: issue B-stage(H+2) FIRST, pin order with
// sched_barrier(0), then plain A(H+1) loads. Invariant: in vmem issue
// order, B(H+1) < A(H) (established in body H-1), so the compiler's own
// wait for A(H) before the MFMAs implies B(H+1) retired (in-order vmcnt);
// the raw s_barrier then publishes it block-wide before body H+1 reads it.
#define BODY(H, AF_USE, AF_LOAD)                                           \
  {                                                                        \
    if ((H) < 34) {                                                        \
      char* sd = lds + st_ * 8192;                                         \
      const int hn = (H) + 2, off_ = hn >> 2, qq = hn & 3;                 \
      const int dh_ = off_ / 3, dw_ = off_ - dh_ * 3;                      \
      const int dB = (dh_ * 58 + dw_) * 256 + qq * 64;                     \
      gl2lds16((const char*)xp + sbB[0] + dB, sd + dbB[0]);                \
      gl2lds16((const char*)xp + sbB[1] + dB, sd + dbB[1]);                \
    }                                                                      \
    __builtin_amdgcn_sched_barrier(0);                                     \
    if ((H) < 35) {                                                        \
      const unsigned short* aN = wt + (size_t)((H) + 1) * 8192 + aSub;     \
      _Pragma("unroll")                                                    \
      for (int i_ = 0; i_ < 8; ++i_)                                       \
        AF_LOAD[i_] = *(const short8*)(aN + i_ * 512);                     \
    }                                                                      \
    short8 bfr[4];                                                         \
    {                                                                      \
      const char* la = lds + bf_ * 8192;                                   \
      bfr[0] = *(const short8*)(la + bOff);                                \
      bfr[1] = *(const short8*)(la + bOff + 1024);                         \
      bfr[2] = *(const short8*)(la + bOff + 2048);                         \
      bfr[3] = *(const short8*)(la + bOff + 3072);                         \
    }                                                                      \
    __builtin_amdgcn_s_setprio(1);                                         \
    _Pragma("unroll")                                                      \
    for (int i_ = 0; i_ < 8; ++i_) {                                       \
      _Pragma("unroll")                                                    \
      for (int j_ = 0; j_ < 4; ++j_)                                       \
        acc[i_][j_] = __builtin_amdgcn_mfma_f32_16x16x32_bf16(             \
            AF_USE[i_], bfr[j_], acc[i_][j_], 0, 0, 0);                    \
    }                                                                      \
    __builtin_amdgcn_s_setprio(0);                                         \
    if ((H) < 35) __builtin_amdgcn_s_barrier();                            \
    bf_ = (bf_ == 2) ? 0 : bf_ + 1;                                        \
    st_ = (st_ == 2) ? 0 : st_ + 1;                                        \
  }

    int bf_ = 0, st_ = 2;
    for (int h = 0; h < 36; h += 2) {
        BODY(h,     afA, afB);
        BODY(h + 1, afB, afA);
    }

    // ---- epilogue: D[row=cout(quad*4+reg)][col=spatial(lane&15)] ----------
    const int q4 = (lane >> 4) << 2;
    int nb[4], ns[4];
#pragma unroll
    for (int j = 0; j < 4; ++j) {
        const int n = ntile * 128 + wn * 64 + j * 16 + fr;
        nb[j] = n / 3136;
        ns[j] = n - nb[j] * 3136;
    }
#pragma unroll
    for (int i = 0; i < 8; ++i) {
        const int co = wm * 128 + i * 16 + q4;
        float bv[4];
        if (isbf) {
            const ushort4 bb = *(const ushort4*)((const unsigned short*)bias + co);
            bv[0] = bf2f(bb.x); bv[1] = bf2f(bb.y);
            bv[2] = bf2f(bb.z); bv[3] = bf2f(bb.w);
        } else {
            const float4 bb = *(const float4*)((const float*)bias + co);
            bv[0] = bb.x; bv[1] = bb.y; bv[2] = bb.z; bv[3] = bb.w;
        }
#pragma unroll
        for (int j = 0; j < 4; ++j) {
#pragma unroll
            for (int r = 0; r < 4; ++r) {
                const float v = acc[i][j][r] + bv[r];
                const size_t o = (size_t)nb[j] * 802816 +
                                 (size_t)(co + r) * 3136 + ns[j];
                if (isbf) ((unsigned short*)out)[o] = f2bf(v);
                else      ((float*)out)[o] = v;
            }
        }
    }
}

// ---------------- fallback: naive direct conv fp32 (if ws too small) -------
__global__ void conv_naive(const float* __restrict__ x,
                           const float* __restrict__ w,
                           const float* __restrict__ bias,
                           float* __restrict__ out) {
    long long i = (long long)blockIdx.x * 256 + threadIdx.x;
    if (i >= 25690112LL) return;
    int wo = (int)(i % 56); long long t = i / 56;
    int ho = (int)(t % 56); t /= 56;
    int co = (int)(t % 256); int b = (int)(t / 256);
    float acc = bias[co];
    for (int ci = 0; ci < 128; ++ci)
        for (int dh = 0; dh < 3; ++dh) {
            int hi = ho + dh - 1; if ((unsigned)hi >= 56u) continue;
            for (int dw = 0; dw < 3; ++dw) {
                int wi = wo + dw - 1; if ((unsigned)wi >= 56u) continue;
                acc += x[((size_t)(b * 128 + ci) * 56 + hi) * 56 + wi] *
                       w[((co * 128 + ci) * 3 + dh) * 3 + dw];
            }
        }
    out[i] = acc;
}

extern "C" void kernel_launch(void* const* d_in, const int* in_sizes, int n_in,
                              void* d_out, int out_size, void* d_ws, size_t ws_size,
                              hipStream_t stream) {
    const void* x    = d_in[0];
    const void* w    = d_in[1];
    const void* bias = d_in[2];
    // d_in[3] = approximate (scalar, does not affect exact math) — unused.

    const size_t xp_bytes = (size_t)32 * 58 * 58 * 128 * 2;   // 27,557,888
    const size_t wt_off   = xp_bytes;
    const size_t wt_bytes = (size_t)9 * 256 * 128 * 2;        // 589,824
    const size_t need     = wt_off + wt_bytes;

    if (ws_size >= need) {
        unsigned short* xp = (unsigned short*)d_ws;
        unsigned short* wt = (unsigned short*)((char*)d_ws + wt_off);
        x_repack<<<32 * 58, 256, 0, stream>>>(x, xp);
        wt_repack<<<144, 256, 0, stream>>>(w, wt);
        conv_mfma<<<dim3(784, 1, 1), 256, 0, stream>>>(xp, wt, bias, d_out, x);
    } else {
        conv_naive<<<(25690112 + 255) / 256, 256, 0, stream>>>(
            (const float*)x, (const float*)w, (const float*)bias, (float*)d_out);
    }
}

// Round 12
// 220.705 us; speedup vs baseline: 1.4901x; 1.0471x over previous
//
#include <hip/hip_runtime.h>

// CustomConv2d: 3x3 conv, stride 1, pad 1. B=32, Cin=128, H=W=56, Cout=256.
// fp32 in/out (round-1 NaN proved it); per-wave dtype self-detection keeps
// robustness without a separate serialized detect dispatch.
//
// Implicit GEMM, internally bf16. M=cout(256), N=b*h*w(100352), K=cin*9(1152).
// Round-17: every barrier-synced structure pinned at 21-29% MfmaUtil
// (r9 86.5us, lockstep 93, drain 109, ordering 101): per-half s_barrier
// convoys all waves on the slowest staged load (~2200cyc dead per slot vs
// ~1000 mem + 1240 MFMA). This round removes ALL barriers:
//   - each wave owns PRIVATE LDS: 3 x 4KB buffers for its own 64 B-cols,
//     staged by itself via coalesced gl2lds16 (fixes r13's 16-segment
//     scatter), read only by itself -> no cross-wave LDS sharing at all
//   - A in registers from fragment-order wt (ping-pong, plain C++ loads)
//   - wave-local ordering invariant (container-proven in r15): per body,
//     stage(h+2) issued BEFORE A(h+1) loads (sched_barrier(0) pins);
//     compiler's own vmcnt wait on A(h) regs => stage(h+1) retired
//     (in-order vmem, m135); sched_barrier(0) after the MFMA cluster pins
//     body h+1's ds_reads behind it. One manual vmcnt(8) in the prologue.
//     NO s_barrier / __syncthreads in conv_mfma at all.
//   - B staging duplicated across wm-pairs (x2): LDS 48KB/block, B global
//     reads stay L2-hot; 3 blocks/CU (LDS 144/160KB, ~240 unified regs)
//     -> 3 independent wave-streams per SIMD fill each other's stalls
//   - per wave per body: 4 gl2lds16 + 8 A-loads + 4 ds_read_b128 + 32 MFMA
//   - same XOR chunk swizzle (0 conflicts measured), XCD swizzle 784=8x98

typedef __attribute__((ext_vector_type(8))) short short8;
typedef __attribute__((ext_vector_type(4))) float floatx4;

typedef __attribute__((address_space(1))) const void* gas_ptr;
typedef __attribute__((address_space(3))) void* las_ptr;

__device__ static inline void gl2lds16(const void* g, void* l) {
    __builtin_amdgcn_global_load_lds((gas_ptr)g, (las_ptr)l, 16, 0, 0);
}

__device__ static inline float bf2f(unsigned short u) {
    union { unsigned int i; float f; } x; x.i = ((unsigned int)u) << 16; return x.f;
}
__device__ static inline unsigned short f2bf(float f) {
    union { float f; unsigned int i; } x; x.f = f;
    unsigned int r = (x.i + 0x7FFFu + ((x.i >> 16) & 1u)) >> 16;  // RNE
    return (unsigned short)r;
}

// Per-wave dtype sniff: low halves of fp32 words are random mantissa bits
// (~19% plausible bf16 exponents); true bf16 data is ~100% plausible.
// Uniform across the wave via ballot; requires all 64 lanes active.
__device__ static inline bool wave_detect_bf16(const unsigned int* __restrict__ p) {
    const int lane = threadIdx.x & 63;
    int cnt = 0;
#pragma unroll
    for (int r = 0; r < 4; ++r) {
        unsigned int w = p[r * 64 + lane];
        unsigned short lo = (unsigned short)(w & 0xFFFFu);
        int e = (lo >> 7) & 0xFF;
        bool plaus = (lo == 0) || (e >= 96 && e <= 144);
        cnt += (int)__popcll(__ballot(plaus));
    }
    return cnt >= 205;   // >=80% of 256 sampled halves
}

// ------ weight repack -> fragment order [36][2][8][64] 16B chunks ---------
// Chunk (h=off*4+q, wm, i, lane) holds A[co=wm*128+i*16+(lane&15)]
// [ci=q*32+(lane>>4)*8 .. +8) as 8 bf16. conv_mfma lane l then loads its
// MFMA A-fragment at ushort index h*8192 + wm*4096 + i*512 + l*8.
__global__ void wt_repack(const void* __restrict__ wsrc,
                          unsigned short* __restrict__ wt) {
    const bool isbf = wave_detect_bf16((const unsigned int*)wsrc);
    int idx  = blockIdx.x * 256 + threadIdx.x;   // 36864 chunks, grid=144
    int lane = idx & 63;
    int i    = (idx >> 6) & 7;
    int wm   = (idx >> 9) & 1;
    int q    = (idx >> 10) & 3;
    int off  = idx >> 12;                        // 0..8 = dh*3+dw
    int co   = wm * 128 + i * 16 + (lane & 15);
    int ci0  = q * 32 + (lane >> 4) * 8;
    union { unsigned short s[8]; uint4 u; } pk;
#pragma unroll
    for (int e = 0; e < 8; ++e) {
        size_t s = (size_t)(co * 128 + ci0 + e) * 9 + off;
        float v = isbf ? bf2f(((const unsigned short*)wsrc)[s])
                       : ((const float*)wsrc)[s];
        pk.s[e] = f2bf(v);
    }
    *(uint4*)(wt + (size_t)idx * 8) = pk.u;
}

// ------- x NCHW -> padded NHWC bf16 [32][58][58][128], LDS transpose -------
__global__ __launch_bounds__(256) void x_repack(
    const void* __restrict__ xsrc, unsigned short* __restrict__ xp) {
    __shared__ unsigned short tile[56 * 130];   // pad 130: conflict-free
    const int bh  = blockIdx.x;                 // 32*58 blocks
    const int b   = bh / 58, hp = bh - b * 58;  // hp in [0,58)
    const int tid = threadIdx.x;
    unsigned short* row = xp + (size_t)(b * 58 + hp) * 58 * 128;
    if (hp == 0 || hp == 57) {                  // top/bottom pad rows
        uint4 z; z.x = z.y = z.z = z.w = 0u;
        uint4* r = (uint4*)row;
        for (int t = tid; t < 928; t += 256) r[t] = z;
        return;
    }
    const bool isbf = wave_detect_bf16((const unsigned int*)xsrc);
    const int h = hp - 1;
    if (isbf) {
        const unsigned short* xs =
            (const unsigned short*)xsrc + (size_t)b * 128 * 3136 + h * 56;
#pragma unroll
        for (int it = 0; it < 7; ++it) {        // 1792 items = 128ci x 14 w4
            int idx = it * 256 + tid;
            int ci = idx / 14, w4 = idx - ci * 14;
            ushort4 v = *(const ushort4*)(xs + (size_t)ci * 3136 + w4 * 4);
            tile[(w4 * 4 + 0) * 130 + ci] = v.x;
            tile[(w4 * 4 + 1) * 130 + ci] = v.y;
            tile[(w4 * 4 + 2) * 130 + ci] = v.z;
            tile[(w4 * 4 + 3) * 130 + ci] = v.w;
        }
    } else {
        const float* xs = (const float*)xsrc + (size_t)b * 128 * 3136 + h * 56;
#pragma unroll
        for (int it = 0; it < 7; ++it) {
            int idx = it * 256 + tid;
            int ci = idx / 14, w4 = idx - ci * 14;
            float4 v = *(const float4*)(xs + (size_t)ci * 3136 + w4 * 4);
            tile[(w4 * 4 + 0) * 130 + ci] = f2bf(v.x);
            tile[(w4 * 4 + 1) * 130 + ci] = f2bf(v.y);
            tile[(w4 * 4 + 2) * 130 + ci] = f2bf(v.z);
            tile[(w4 * 4 + 3) * 130 + ci] = f2bf(v.w);
        }
    }
    __syncthreads();
#pragma unroll
    for (int it = 0; it < 4; ++it) {
        int k = it * 256 + tid;                 // 928 chunks of 16B
        if (k >= 928) break;
        int wq = k >> 4, cc = k & 15;
        uint4 v;
        if (wq == 0 || wq == 57) { v.x = v.y = v.z = v.w = 0u; }
        else {
            const unsigned short* p = &tile[(wq - 1) * 130 + cc * 8];
            union { unsigned short s[8]; uint4 u; } pk;
#pragma unroll
            for (int j = 0; j < 8; ++j) pk.s[j] = p[j];
            v = pk.u;
        }
        *(uint4*)(row + wq * 128 + cc * 8) = v;
    }
}

// -------- main: 4-wave 128x64-per-wave implicit GEMM, 256x128 tile ---------
// BARRIER-FREE. A from global (fragment-order wt, register ping-pong); B via
// PER-WAVE-PRIVATE LDS (3 x 4KB buffers each), staged 2 halves ahead by the
// owning wave. h=(dh*3+dw)*4+q, 36 halves.
__global__ __launch_bounds__(256, 2) void conv_mfma(
    const unsigned short* __restrict__ xp,   // [32][58][58][128] bf16
    const unsigned short* __restrict__ wt,   // fragment-order, 589824 B
    const void* __restrict__ bias,           // [256] fp32 or bf16
    void* __restrict__ out,                  // [32][256][56][56] fp32 or bf16
    const void* __restrict__ xorig)          // for dtype sniff only
{
    __shared__ __align__(16) char lds[49152];   // 4 waves x 3 bufs x 4KB
    const int tid   = threadIdx.x;
    const int lane  = tid & 63;
    const int wv    = tid >> 6;        // 0..3
    const int bid   = blockIdx.x;
    const int ntile = (bid & 7) * 98 + (bid >> 3);   // XCD swizzle, 784=8x98

    const bool isbf = wave_detect_bf16((const unsigned int*)xorig);

    // ---- B staging setup: 4 x 1KB chunks per half, all owned by this wave.
    // Chunk c covers the wave's rows [c*16, c*16+16); lane writes row
    // c*16 + (lane>>2), phys slot lane&3, content k-chunk clg.
    const int clg  = (lane & 3) ^ ((lane >> 3) & 3);
    const int rsub = lane >> 2;
    const int wm = wv >> 1;            // 0..1  (M: 128 couts per wave)
    const int wn = wv & 1;             // 0..1  (N: 64 cols per wave)
    unsigned sbB[4]; int dbB[4];
#pragma unroll
    for (int c = 0; c < 4; ++c) {
        const int n = ntile * 128 + wn * 64 + c * 16 + rsub;
        const int b = n / 3136, rem = n - b * 3136;
        const int hh = rem / 56, ww = rem - hh * 56;
        sbB[c] = (unsigned)(((b * 58 + hh) * 58 + ww) * 256 + clg * 16);
        dbB[c] = wv * 12288 + c * 1024;          // + buf*4096 at use site
    }

    // ---- fragment setup ---------------------------------------------------
    const int fr = lane & 15;
    const int ph = (lane >> 4) ^ ((fr >> 1) & 3);
    const int bOff = wv * 12288 + fr * 64 + ph * 16;  // + buf*4096 + j*1024
    const int aSub = wm * 4096 + lane * 8;            // ushort units

    floatx4 acc[8][4] = {};
    short8 afA[8], afB[8];

    // ---- prologue: stage B(0)->buf0, B(1)->buf1 (own), then A(0) ---------
#pragma unroll
    for (int c = 0; c < 4; ++c)
        gl2lds16((const char*)xp + sbB[c], lds + dbB[c]);
#pragma unroll
    for (int c = 0; c < 4; ++c)
        gl2lds16((const char*)xp + sbB[c] + 64, lds + 4096 + dbB[c]);
    __builtin_amdgcn_sched_barrier(0);
#pragma unroll
    for (int i_ = 0; i_ < 8; ++i_)
        afA[i_] = *(const short8*)(wt + aSub + i_ * 512);
    // wave-local gate: stages (8 ops) retired, A(0)'s 8 stay in flight
    __builtin_amdgcn_s_waitcnt(0x3F78);   // vmcnt(8)
    __builtin_amdgcn_sched_barrier(0);

// Body for half H: stage own B(H+2) FIRST (order pinned), then plain A(H+1)
// loads. Invariant (wave-local, compiler-tracked): stage(X) issued before
// A(X-1); the compiler's vmcnt wait on A(X-1) regs before body X-1's MFMAs
// implies stage(X) retired (in-order vmem); the sched_barrier(0) after each
// MFMA cluster pins body X's ds_reads behind that wait. No s_barrier.
#define BODY(H, AF_USE, AF_LOAD)                                           \
  {                                                                        \
    if ((H) < 34) {                                                        \
      char* sd = lds + st_ * 4096;                                         \
      const int hn = (H) + 2, off_ = hn >> 2, qq = hn & 3;                 \
      const int dh_ = off_ / 3, dw_ = off_ - dh_ * 3;                      \
      const int dB = (dh_ * 58 + dw_) * 256 + qq * 64;                     \
      gl2lds16((const char*)xp + sbB[0] + dB, sd + dbB[0]);                \
      gl2lds16((const char*)xp + sbB[1] + dB, sd + dbB[1]);                \
      gl2lds16((const char*)xp + sbB[2] + dB, sd + dbB[2]);                \
      gl2lds16((const char*)xp + sbB[3] + dB, sd + dbB[3]);                \
    }                                                                      \
    __builtin_amdgcn_sched_barrier(0);                                     \
    if ((H) < 35) {                                                        \
      const unsigned short* aN = wt + (size_t)((H) + 1) * 8192 + aSub;     \
      _Pragma("unroll")                                                    \
      for (int i_ = 0; i_ < 8; ++i_)                                       \
        AF_LOAD[i_] = *(const short8*)(aN + i_ * 512);                     \
    }                                                                      \
    short8 bfr[4];                                                         \
    {                                                                      \
      const char* la = lds + bf_ * 4096;                                   \
      bfr[0] = *(const short8*)(la + bOff);                                \
      bfr[1] = *(const short8*)(la + bOff + 1024);                         \
      bfr[2] = *(const short8*)(la + bOff + 2048);                         \
      bfr[3] = *(const short8*)(la + bOff + 3072);                         \
    }                                                                      \
    __builtin_amdgcn_s_setprio(1);                                         \
    _Pragma("unroll")                                                      \
    for (int i_ = 0; i_ < 8; ++i_) {                                       \
      _Pragma("unroll")                                                    \
      for (int j_ = 0; j_ < 4; ++j_)                                       \
        acc[i_][j_] = __builtin_amdgcn_mfma_f32_16x16x32_bf16(             \
            AF_USE[i_], bfr[j_], acc[i_][j_], 0, 0, 0);                    \
    }                                                                      \
    __builtin_amdgcn_s_setprio(0);                                         \
    __builtin_amdgcn_sched_barrier(0);                                     \
    bf_ = (bf_ == 2) ? 0 : bf_ + 1;                                        \
    st_ = (st_ == 2) ? 0 : st_ + 1;                                        \
  }

    int bf_ = 0, st_ = 2;
    for (int h = 0; h < 36; h += 2) {
        BODY(h,     afA, afB);
        BODY(h + 1, afB, afA);
    }

    // ---- epilogue: D[row=cout(quad*4+reg)][col=spatial(lane&15)] ----------
    const int q4 = (lane >> 4) << 2;
    int nb[4], ns[4];
#pragma unroll
    for (int j = 0; j < 4; ++j) {
        const int n = ntile * 128 + wn * 64 + j * 16 + fr;
        nb[j] = n / 3136;
        ns[j] = n - nb[j] * 3136;
    }
#pragma unroll
    for (int i = 0; i < 8; ++i) {
        const int co = wm * 128 + i * 16 + q4;
        float bv[4];
        if (isbf) {
            const ushort4 bb = *(const ushort4*)((const unsigned short*)bias + co);
            bv[0] = bf2f(bb.x); bv[1] = bf2f(bb.y);
            bv[2] = bf2f(bb.z); bv[3] = bf2f(bb.w);
        } else {
            const float4 bb = *(const float4*)((const float*)bias + co);
            bv[0] = bb.x; bv[1] = bb.y; bv[2] = bb.z; bv[3] = bb.w;
        }
#pragma unroll
        for (int j = 0; j < 4; ++j) {
#pragma unroll
            for (int r = 0; r < 4; ++r) {
                const float v = acc[i][j][r] + bv[r];
                const size_t o = (size_t)nb[j] * 802816 +
                                 (size_t)(co + r) * 3136 + ns[j];
                if (isbf) ((unsigned short*)out)[o] = f2bf(v);
                else      ((float*)out)[o] = v;
            }
        }
    }
}

// ---------------- fallback: naive direct conv fp32 (if ws too small) -------
__global__ void conv_naive(const float* __restrict__ x,
                           const float* __restrict__ w,
                           const float* __restrict__ bias,
                           float* __restrict__ out) {
    long long i = (long long)blockIdx.x * 256 + threadIdx.x;
    if (i >= 25690112LL) return;
    int wo = (int)(i % 56); long long t = i / 56;
    int ho = (int)(t % 56); t /= 56;
    int co = (int)(t % 256); int b = (int)(t / 256);
    float acc = bias[co];
    for (int ci = 0; ci < 128; ++ci)
        for (int dh = 0; dh < 3; ++dh) {
            int hi = ho + dh - 1; if ((unsigned)hi >= 56u) continue;
            for (int dw = 0; dw < 3; ++dw) {
                int wi = wo + dw - 1; if ((unsigned)wi >= 56u) continue;
                acc += x[((size_t)(b * 128 + ci) * 56 + hi) * 56 + wi] *
                       w[((co * 128 + ci) * 3 + dh) * 3 + dw];
            }
        }
    out[i] = acc;
}

extern "C" void kernel_launch(void* const* d_in, const int* in_sizes, int n_in,
                              void* d_out, int out_size, void* d_ws, size_t ws_size,
                              hipStream_t stream) {
    const void* x    = d_in[0];
    const void* w    = d_in[1];
    const void* bias = d_in[2];
    // d_in[3] = approximate (scalar, does not affect exact math) — unused.

    const size_t xp_bytes = (size_t)32 * 58 * 58 * 128 * 2;   // 27,557,888
    const size_t wt_off   = xp_bytes;
    const size_t wt_bytes = (size_t)9 * 256 * 128 * 2;        // 589,824
    const size_t need     = wt_off + wt_bytes;

    if (ws_size >= need) {
        unsigned short* xp = (unsigned short*)d_ws;
        unsigned short* wt = (unsigned short*)((char*)d_ws + wt_off);
        x_repack<<<32 * 58, 256, 0, stream>>>(x, xp);
        wt_repack<<<144, 256, 0, stream>>>(w, wt);
        conv_mfma<<<dim3(784, 1, 1), 256, 0, stream>>>(xp, wt, bias, d_out, x);
    } else {
        conv_naive<<<(25690112 + 255) / 256, 256, 0, stream>>>(
            (const float*)x, (const float*)w, (const float*)bias, (float*)d_out);
    }
}